// Round 1
// baseline (1125.676 us; speedup 1.0000x reference)
//
#include <hip/hip_runtime.h>

// HPCrnn: 100-step RNN over batch 32768.
// basal_kernel: precompute basal[t][n] = sum_k exp(-(((t+1)-c_k)/5)^2/2) * Wbasal[k][n]
// rnn_kernel:  per block = 32 batch rows, 8 waves; weights register-resident as bf16
//              MFMA B-fragments; ec5/ec3 state fp32 in regs (MFMA C-layout);
//              ec3/ca1 staged bf16 in LDS per step as MFMA A-operands.

#define TSTEPS 100
#define ROWS   32
#define SPAD   264   // stage row stride in bf16 elems: 528 B = 33*16B (16B aligned, 2-way conflict max)

typedef __bf16 bf16x8 __attribute__((ext_vector_type(8)));
typedef float  f32x4  __attribute__((ext_vector_type(4)));

__global__ void basal_kernel(const float* __restrict__ Wbasal, float* __restrict__ basal) {
    const int t = blockIdx.x;      // 0..99  -> x = t+1
    const int n = threadIdx.x;     // 0..255
    __shared__ float ca3s[256];
    const float x = (float)(t + 1);
    const float c = (float)n * (100.0f / 255.0f);   // linspace(0,100,256)
    const float d = (x - c) * (1.0f / 5.0f);
    ca3s[n] = expf(-0.5f * d * d);
    __syncthreads();
    float s = 0.f;
    #pragma unroll 8
    for (int k = 0; k < 256; ++k) s += ca3s[k] * Wbasal[k * 256 + n];
    basal[t * 256 + n] = s;
}

__global__ __launch_bounds__(512, 2) void rnn_kernel(
    const float* __restrict__ cue, const float* __restrict__ ec5_init,
    const float* __restrict__ Wap, const float* __restrict__ Wc,
    const float* __restrict__ Wact, const float* __restrict__ bias,
    const float* __restrict__ basal, float* __restrict__ out)
{
    const int tid  = threadIdx.x;
    const int wave = tid >> 6;         // 0..7
    const int lane = tid & 63;
    const int quad = lane >> 4;        // 0..3
    const int l16  = lane & 15;
    const int wb   = wave * 32;        // this wave's 32-column slice (both GEMMs)
    const int row0 = blockIdx.x * ROWS;

    __shared__ __bf16 sE[ROWS * SPAD];   // ec3 stage (A of GEMM1), [r][e]
    __shared__ __bf16 sC[ROWS * SPAD];   // ca1 stage (A of GEMM2), [r][j]

    // ---- preload weight B-fragments (bf16) into registers ----
    // B[k][n]: n = lane&15 (+16*nt), k = quad*8 + j (+32*kc)
    bf16x8 WapF[2][8], WcF[2][8];
    #pragma unroll
    for (int nt = 0; nt < 2; ++nt) {
        const int n = wb + nt * 16 + l16;
        #pragma unroll
        for (int kc = 0; kc < 8; ++kc) {
            #pragma unroll
            for (int j = 0; j < 8; ++j) {
                const int k = kc * 32 + quad * 8 + j;
                WapF[nt][kc][j] = (__bf16)Wap[k * 256 + n];
                WcF[nt][kc][j]  = (__bf16)Wc[k * 256 + n];
            }
        }
    }
    float biasv[2];
    #pragma unroll
    for (int nt = 0; nt < 2; ++nt) biasv[nt] = bias[wb + nt * 16 + l16];

    // ---- fp32 state in C-layout: row = rt*16 + quad*4 + i, col = wb + nt*16 + l16 ----
    float ec5v[2][2][4], ec3v[2][2][4];
    #pragma unroll
    for (int rt = 0; rt < 2; ++rt)
        #pragma unroll
        for (int nt = 0; nt < 2; ++nt)
            #pragma unroll
            for (int i = 0; i < 4; ++i) {
                const int r = row0 + rt * 16 + quad * 4 + i;
                const int e = wb + nt * 16 + l16;
                ec5v[rt][nt][i] = ec5_init[r * 256 + e];
                ec3v[rt][nt][i] = 0.f;
            }

    for (int t = 0; t < TSTEPS; ++t) {
        __syncthreads();   // ec3 stage writes (prev step) visible; also covers ca1-stage WAR

        // ---- GEMM1: ca1acc = ec3 @ Wapical  (skipped at t=0: ec3=0 -> acc=0) ----
        f32x4 acc[2][2] = {};
        if (t > 0) {
            #pragma unroll
            for (int rt = 0; rt < 2; ++rt) {
                #pragma unroll
                for (int kc = 0; kc < 8; ++kc) {
                    const bf16x8 a = *(const bf16x8*)&sE[(rt * 16 + l16) * SPAD + kc * 32 + quad * 8];
                    #pragma unroll
                    for (int nt = 0; nt < 2; ++nt)
                        acc[rt][nt] = __builtin_amdgcn_mfma_f32_16x16x32_bf16(
                            a, WapF[nt][kc], acc[rt][nt], 0, 0, 0);
                }
            }
        }

        const float b0 = basal[t * 256 + wb + l16];
        const float b1 = basal[t * 256 + wb + 16 + l16];

        // ---- ca1 = relu(basal_t * (1 + sigmoid(x)) - bias); stage bf16 ----
        #pragma unroll
        for (int rt = 0; rt < 2; ++rt)
            #pragma unroll
            for (int nt = 0; nt < 2; ++nt)
                #pragma unroll
                for (int i = 0; i < 4; ++i) {
                    const float x = acc[rt][nt][i];
                    const float s = 1.0f / (1.0f + __expf(-x));
                    const float bt = nt ? b1 : b0;
                    float c = bt * (1.0f + s) - biasv[nt];
                    c = fmaxf(c, 0.0f);
                    sC[(rt * 16 + quad * 4 + i) * SPAD + wb + nt * 16 + l16] = (__bf16)c;
                }

        __syncthreads();   // ca1 stage visible; also covers ec3-stage WAR

        // ---- GEMM2: dacc = ca1 @ Wca1ec5 ----
        f32x4 acc2[2][2] = {};
        #pragma unroll
        for (int rt = 0; rt < 2; ++rt) {
            #pragma unroll
            for (int kc = 0; kc < 8; ++kc) {
                const bf16x8 a = *(const bf16x8*)&sC[(rt * 16 + l16) * SPAD + kc * 32 + quad * 8];
                #pragma unroll
                for (int nt = 0; nt < 2; ++nt)
                    acc2[rt][nt] = __builtin_amdgcn_mfma_f32_16x16x32_bf16(
                        a, WcF[nt][kc], acc2[rt][nt], 0, 0, 0);
            }
        }

        // ---- ec5 = clip(ec5 + dacc); ec3 = clip(ec5*ec3 + (t==0 ? cue : 0)); stage ec3 bf16 ----
        #pragma unroll
        for (int rt = 0; rt < 2; ++rt)
            #pragma unroll
            for (int nt = 0; nt < 2; ++nt)
                #pragma unroll
                for (int i = 0; i < 4; ++i) {
                    float e5 = ec5v[rt][nt][i] + acc2[rt][nt][i];
                    e5 = fminf(fmaxf(e5, 0.0f), 1.0f);
                    float e3 = e5 * ec3v[rt][nt][i];
                    if (t == 0) {
                        const int r = row0 + rt * 16 + quad * 4 + i;
                        const int e = wb + nt * 16 + l16;
                        e3 += cue[r * 256 + e];
                    }
                    e3 = fminf(fmaxf(e3, 0.0f), 1.0f);
                    ec5v[rt][nt][i] = e5;
                    ec3v[rt][nt][i] = e3;
                    sE[(rt * 16 + quad * 4 + i) * SPAD + wb + nt * 16 + l16] = (__bf16)e3;
                }
    }

    __syncthreads();
    // ---- out = ca1_final @ Waction, from sC (bf16 stage) ----
    // 64 outputs (32 rows x 2 actions), 8 threads each summing 32 terms
    {
        const int o   = tid >> 3;        // 0..63
        const int r   = o >> 1;          // 0..31
        const int a   = o & 1;
        const int sub = tid & 7;
        float p = 0.f;
        #pragma unroll 8
        for (int j = sub * 32; j < sub * 32 + 32; ++j)
            p += (float)sC[r * SPAD + j] * Wact[j * 2 + a];
        p += __shfl_xor(p, 1);
        p += __shfl_xor(p, 2);
        p += __shfl_xor(p, 4);
        if (sub == 0) out[(row0 + r) * 2 + a] = p;
    }
}

extern "C" void kernel_launch(void* const* d_in, const int* in_sizes, int n_in,
                              void* d_out, int out_size, void* d_ws, size_t ws_size,
                              hipStream_t stream) {
    const float* cue      = (const float*)d_in[0];
    const float* ec5_init = (const float*)d_in[1];
    const float* Wapical  = (const float*)d_in[2];
    const float* Wbasal   = (const float*)d_in[3];
    const float* Wca1ec5  = (const float*)d_in[4];
    const float* Waction  = (const float*)d_in[5];
    const float* ca1bias  = (const float*)d_in[6];
    float* out = (float*)d_out;
    float* basal = (float*)d_ws;   // 100*256 fp32 = 100 KB

    basal_kernel<<<TSTEPS, 256, 0, stream>>>(Wbasal, basal);
    rnn_kernel<<<32768 / ROWS, 512, 0, stream>>>(cue, ec5_init, Wapical, Wca1ec5,
                                                 Waction, ca1bias, basal, out);
}

// Round 2
// 1121.487 us; speedup vs baseline: 1.0037x; 1.0037x over previous
//
#include <hip/hip_runtime.h>

// HPCrnn: 100-step RNN over batch 32768 — transposed formulation.
// All GEMMs computed as state^T = W^T @ state^T with 32x32x16 bf16 MFMA:
//   - weights register-resident as A-fragments (W^T), 64 VGPRs each
//   - state (ec5/ec3) fp32 in registers in MFMA C/D^T layout:
//       lane holds batch-row r = lane&31, features f(v) = wb + (v&3) + 8*(v>>2) + 4*(lane>>5)
//   - D^T layout gives 4 CONSECUTIVE features per reg-quad -> packed ds_write_b64
//     stage writes (8/step vs 32 scalar b16 in R1; kills the 1e8 bank conflicts)
//   - stage buffers [row][feature] row-major -> B-operand ds_read_b128 with
//     immediate offsets

#define TSTEPS 100
#define ROWS   32
#define RS     264   // stage row stride in bf16 elems (528 B; 16B-aligned reads)

typedef __bf16 bf16x8  __attribute__((ext_vector_type(8)));
typedef __bf16 bf16x4  __attribute__((ext_vector_type(4)));
typedef float  f32x16  __attribute__((ext_vector_type(16)));
typedef float  f32x4   __attribute__((ext_vector_type(4)));

__global__ void basal_kernel(const float* __restrict__ Wbasal, float* __restrict__ basal) {
    const int t = blockIdx.x;      // 0..99  -> x = t+1
    const int n = threadIdx.x;     // 0..255
    __shared__ float ca3s[256];
    const float x = (float)(t + 1);
    const float c = (float)n * (100.0f / 255.0f);   // linspace(0,100,256)
    const float d = (x - c) * (1.0f / 5.0f);
    ca3s[n] = expf(-0.5f * d * d);
    __syncthreads();
    float s = 0.f;
    #pragma unroll 8
    for (int k = 0; k < 256; ++k) s += ca3s[k] * Wbasal[k * 256 + n];
    basal[t * 256 + n] = s;
}

__global__ __launch_bounds__(512, 2) void rnn_kernel(
    const float* __restrict__ cue, const float* __restrict__ ec5_init,
    const float* __restrict__ Wap, const float* __restrict__ Wc,
    const float* __restrict__ Wact, const float* __restrict__ bias,
    const float* __restrict__ basal, float* __restrict__ out)
{
    const int tid  = threadIdx.x;
    const int wave = tid >> 6;         // 0..7
    const int lane = tid & 63;
    const int L    = lane & 31;        // batch row within block (MFMA n / C col)
    const int H    = lane >> 5;        // half-wave (k-offset selector)
    const int wb   = wave * 32;        // this wave's 32-feature output slice
    const int row0 = blockIdx.x * ROWS;

    __shared__ __bf16 sE[ROWS * RS];   // ec3^T stage: [r][e], B of GEMM1
    __shared__ __bf16 sC[ROWS * RS];   // ca1^T stage: [r][p], B of GEMM2

    // ---- weight A-fragments: A[m][k], m = wb+L (output feature), k = kc*16 + H*8 + j ----
    bf16x8 WapF[16], WcF[16];
    #pragma unroll
    for (int kc = 0; kc < 16; ++kc) {
        #pragma unroll
        for (int j = 0; j < 8; ++j) {
            const int k = kc * 16 + H * 8 + j;          // contraction feature
            WapF[kc][j] = (__bf16)Wap[k * 256 + wb + L];  // Wap^T[m][k] = Wap[k][m]
            WcF[kc][j]  = (__bf16)Wc[k * 256 + wb + L];   // Wc^T[m][k]  = Wc[k][m]
        }
    }

    // ---- state in C/D^T layout: lane row r = row0+L, feature f(v) = wb+(v&3)+8*(v>>2)+4*H ----
    float ec5v[16], ec3v[16], biasv[16];
    #pragma unroll
    for (int g = 0; g < 4; ++g) {
        const int f0 = wb + 8 * g + 4 * H;
        const f32x4 e0 = *(const f32x4*)&ec5_init[(row0 + L) * 256 + f0];
        #pragma unroll
        for (int q = 0; q < 4; ++q) {
            ec5v[4 * g + q]  = e0[q];
            ec3v[4 * g + q]  = 0.f;
            biasv[4 * g + q] = bias[f0 + q];
        }
    }

    const int rbase = L * RS + H * 8;        // read base (elems): + kc*16
    const int wbase = L * RS + wb + 4 * H;   // write base (elems): + 8*g

    for (int t = 0; t < TSTEPS; ++t) {
        __syncthreads();   // sE(t-1) visible; sC WAR cleared

        // prefetch basal for this step (consumed after GEMM1)
        f32x4 bq[4];
        #pragma unroll
        for (int g = 0; g < 4; ++g)
            bq[g] = *(const f32x4*)&basal[t * 256 + wb + 8 * g + 4 * H];

        // ---- GEMM1: ca1^T = Wap^T @ ec3^T (skip at t=0: ec3=0) ----
        f32x16 acc = {};
        if (t > 0) {
            #pragma unroll
            for (int kc = 0; kc < 16; ++kc) {
                const bf16x8 b = *(const bf16x8*)&sE[rbase + kc * 16];
                acc = __builtin_amdgcn_mfma_f32_32x32x16_bf16(WapF[kc], b, acc, 0, 0, 0);
            }
        }

        // ---- ca1 = relu(basal*(1+sigmoid(acc)) - bias); pack 4 bf16 -> ds_write_b64 ----
        #pragma unroll
        for (int g = 0; g < 4; ++g) {
            bf16x4 h;
            #pragma unroll
            for (int q = 0; q < 4; ++q) {
                const int v = 4 * g + q;
                const float s = 1.0f / (1.0f + __expf(-acc[v]));
                float c = bq[g][q] * (1.0f + s) - biasv[v];
                h[q] = (__bf16)fmaxf(c, 0.0f);
            }
            *(bf16x4*)&sC[wbase + 8 * g] = h;
        }

        __syncthreads();   // sC visible; sE WAR cleared

        // ---- GEMM2: d(ec5)^T = Wc^T @ ca1^T ----
        f32x16 acc2 = {};
        #pragma unroll
        for (int kc = 0; kc < 16; ++kc) {
            const bf16x8 b = *(const bf16x8*)&sC[rbase + kc * 16];
            acc2 = __builtin_amdgcn_mfma_f32_32x32x16_bf16(WcF[kc], b, acc2, 0, 0, 0);
        }

        // ---- ec5 = clip(ec5+d); ec3 = clip(ec5*ec3 [+ cue at t=0]); pack -> sE ----
        #pragma unroll
        for (int g = 0; g < 4; ++g) {
            f32x4 cq = {};
            if (t == 0)
                cq = *(const f32x4*)&cue[(row0 + L) * 256 + wb + 8 * g + 4 * H];
            bf16x4 h;
            #pragma unroll
            for (int q = 0; q < 4; ++q) {
                const int v = 4 * g + q;
                float e5 = ec5v[v] + acc2[v];
                e5 = fminf(fmaxf(e5, 0.0f), 1.0f);
                float e3 = e5 * ec3v[v];
                if (t == 0) e3 += cq[q];
                e3 = fminf(fmaxf(e3, 0.0f), 1.0f);
                ec5v[v] = e5;
                ec3v[v] = e3;
                h[q] = (__bf16)e3;
            }
            *(bf16x4*)&sE[wbase + 8 * g] = h;
        }
    }

    __syncthreads();
    // ---- out = ca1_final @ Waction, from sC [r][p] bf16 ----
    {
        const int o   = tid >> 3;        // 0..63
        const int r   = o >> 1;          // 0..31
        const int a   = o & 1;
        const int sub = tid & 7;
        float p = 0.f;
        #pragma unroll 8
        for (int j = sub * 32; j < sub * 32 + 32; ++j)
            p += (float)sC[r * RS + j] * Wact[j * 2 + a];
        p += __shfl_xor(p, 1);
        p += __shfl_xor(p, 2);
        p += __shfl_xor(p, 4);
        if (sub == 0) out[(row0 + r) * 2 + a] = p;
    }
}

extern "C" void kernel_launch(void* const* d_in, const int* in_sizes, int n_in,
                              void* d_out, int out_size, void* d_ws, size_t ws_size,
                              hipStream_t stream) {
    const float* cue      = (const float*)d_in[0];
    const float* ec5_init = (const float*)d_in[1];
    const float* Wapical  = (const float*)d_in[2];
    const float* Wbasal   = (const float*)d_in[3];
    const float* Wca1ec5  = (const float*)d_in[4];
    const float* Waction  = (const float*)d_in[5];
    const float* ca1bias  = (const float*)d_in[6];
    float* out = (float*)d_out;
    float* basal = (float*)d_ws;   // 100*256 fp32 = 100 KB

    basal_kernel<<<TSTEPS, 256, 0, stream>>>(Wbasal, basal);
    rnn_kernel<<<32768 / ROWS, 512, 0, stream>>>(cue, ec5_init, Wapical, Wca1ec5,
                                                 Waction, ca1bias, basal, out);
}

// Round 3
// 850.578 us; speedup vs baseline: 1.3234x; 1.3185x over previous
//
#include <hip/hip_runtime.h>

// HPCrnn R3: dual-tile (A/B 16-row) software pipeline, 16x16x32 bf16 MFMA.
// Each step = 4 phases; each phase pairs one tile's GEMM (matrix pipe) with the
// other tile's epilogue (VALU pipe) so both pipes run concurrently:
//   P1: G1_B | e1_A   P2: G2_A | e1_B   P3: G2_B | e2_A   P4: G1_A(t+1) | e2_B
// Weights register-resident as A-fragments (W^T, 128 VGPRs). State fp32 in regs
// (C/D layout: lane holds row L=lane&15, feats f=wb+mt*16+quad*4+r). basal fp32
// and staged states (bf16) in LDS. t=0 peeled (sigmoid(0)=0.5 exact, no GEMM1),
// t=99 peeled (only G1+e1 + Waction dot; ec5/ec3 updates are dead).

#define RS 264   // stage row stride in bf16 elems (16B-aligned reads)

typedef __bf16 bf16x8 __attribute__((ext_vector_type(8)));
typedef __bf16 bf16x4 __attribute__((ext_vector_type(4)));
typedef float  f32x4  __attribute__((ext_vector_type(4)));
typedef float  f32x2  __attribute__((ext_vector_type(2)));

__global__ void basal_kernel(const float* __restrict__ Wbasal, float* __restrict__ basal) {
    const int t = blockIdx.x;      // 0..99  -> x = t+1
    const int n = threadIdx.x;     // 0..255
    __shared__ float ca3s[256];
    const float x = (float)(t + 1);
    const float c = (float)n * (100.0f / 255.0f);   // linspace(0,100,256)
    const float d = (x - c) * (1.0f / 5.0f);
    ca3s[n] = expf(-0.5f * d * d);
    __syncthreads();
    float s = 0.f;
    #pragma unroll 8
    for (int k = 0; k < 256; ++k) s += ca3s[k] * Wbasal[k * 256 + n];
    basal[t * 256 + n] = s;
}

__global__ __launch_bounds__(512, 2) void rnn_kernel(
    const float* __restrict__ cue, const float* __restrict__ ec5_init,
    const float* __restrict__ Wap, const float* __restrict__ Wc,
    const float* __restrict__ Wact, const float* __restrict__ bias,
    const float* __restrict__ basal, float* __restrict__ out)
{
    const int tid  = threadIdx.x;
    const int wave = tid >> 6;         // 0..7
    const int lane = tid & 63;
    const int quad = lane >> 4;        // 0..3
    const int L    = lane & 15;        // batch row within tile
    const int wb   = wave * 32;        // this wave's 32-feature slice
    const int row0 = blockIdx.x * 32;  // tile A: rows row0+L, tile B: rows row0+16+L

    __shared__ __bf16 sEA[16 * RS], sCA[16 * RS], sEB[16 * RS], sCB[16 * RS];
    __shared__ float  sBasal[100 * 256];              // 100 KB
    __shared__ float  sPart[2 * 16 * 2 * 32];         // [tile][L][a][wave*4+quad]

    // ---- basal -> LDS (one-time) ----
    for (int i = tid; i < 6400; i += 512)
        ((f32x4*)sBasal)[i] = ((const f32x4*)basal)[i];

    // ---- weight A-fragments: A[m][k], m = wb+mt*16+(lane&15), k = kc*32+quad*8+j ----
    bf16x8 WapF[2][8], WcF[2][8];
    #pragma unroll
    for (int mt = 0; mt < 2; ++mt) {
        const int m = wb + mt * 16 + L;
        #pragma unroll
        for (int kc = 0; kc < 8; ++kc)
            #pragma unroll
            for (int j = 0; j < 8; ++j) {
                const int k = kc * 32 + quad * 8 + j;
                WapF[mt][kc][j] = (__bf16)Wap[k * 256 + m];   // Wap^T[m][k]
                WcF[mt][kc][j]  = (__bf16)Wc[k * 256 + m];    // Wc^T[m][k]
            }
    }

    // ---- -bias (8 persistent regs) ----
    float nb[2][4];
    #pragma unroll
    for (int mt = 0; mt < 2; ++mt) {
        const f32x4 bv = *(const f32x4*)&bias[wb + mt * 16 + quad * 4];
        #pragma unroll
        for (int r = 0; r < 4; ++r) nb[mt][r] = -bv[r];
    }

    // ---- state fp32 in C/D layout ----
    float ec5A[2][4], ec3A[2][4], ec5B[2][4], ec3B[2][4];
    #pragma unroll
    for (int mt = 0; mt < 2; ++mt) {
        const int f0 = wb + mt * 16 + quad * 4;
        const f32x4 a = *(const f32x4*)&ec5_init[(row0 + L) * 256 + f0];
        const f32x4 b = *(const f32x4*)&ec5_init[(row0 + 16 + L) * 256 + f0];
        #pragma unroll
        for (int r = 0; r < 4; ++r) {
            ec5A[mt][r] = a[r]; ec5B[mt][r] = b[r];
            ec3A[mt][r] = 0.f;  ec3B[mt][r] = 0.f;
        }
    }

    const int rdE = L * RS + quad * 8;        // stage read base (+ kc*32)
    const int wrS = L * RS + wb + quad * 4;   // stage write base (+ mt*16)

    auto gemm = [&](const __bf16* __restrict__ S, const bf16x8 (&W)[2][8], f32x4 (&acc)[2]) {
        #pragma unroll
        for (int kc = 0; kc < 8; ++kc) {
            const bf16x8 v = *(const bf16x8*)&S[rdE + kc * 32];
            acc[0] = __builtin_amdgcn_mfma_f32_16x16x32_bf16(W[0][kc], v, acc[0], 0, 0, 0);
            acc[1] = __builtin_amdgcn_mfma_f32_16x16x32_bf16(W[1][kc], v, acc[1], 0, 0, 0);
        }
    };
    auto e1 = [&](const f32x4 (&acc)[2], const f32x4 (&bas)[2], __bf16* __restrict__ SC) {
        #pragma unroll
        for (int mt = 0; mt < 2; ++mt) {
            bf16x4 h;
            #pragma unroll
            for (int r = 0; r < 4; ++r) {
                const float s = __builtin_amdgcn_rcpf(1.0f + __expf(-acc[mt][r]));
                h[r] = (__bf16)fmaxf(fmaf(bas[mt][r], 1.0f + s, nb[mt][r]), 0.0f);
            }
            *(bf16x4*)&SC[wrS + mt * 16] = h;
        }
    };
    auto e2 = [&](const f32x4 (&acc)[2], float (&e5)[2][4], float (&e3)[2][4],
                  __bf16* __restrict__ SE) {
        #pragma unroll
        for (int mt = 0; mt < 2; ++mt) {
            bf16x4 h;
            #pragma unroll
            for (int r = 0; r < 4; ++r) {
                const float v5 = fminf(fmaxf(e5[mt][r] + acc[mt][r], 0.0f), 1.0f);
                const float v3 = v5 * e3[mt][r];   // both in [0,1] -> clip redundant
                e5[mt][r] = v5; e3[mt][r] = v3;
                h[r] = (__bf16)v3;
            }
            *(bf16x4*)&SE[wrS + mt * 16] = h;
        }
    };

    __syncthreads();   // basal fill visible

    // ===== t = 0 (peeled): ec3=0 -> sigmoid(0)=0.5 exactly; ca1 row-independent =====
    #pragma unroll
    for (int mt = 0; mt < 2; ++mt) {
        const f32x4 bas = *(const f32x4*)&sBasal[wb + mt * 16 + quad * 4];
        bf16x4 h;
        #pragma unroll
        for (int r = 0; r < 4; ++r)
            h[r] = (__bf16)fmaxf(fmaf(bas[r], 1.5f, nb[mt][r]), 0.0f);
        *(bf16x4*)&sCA[wrS + mt * 16] = h;
        *(bf16x4*)&sCB[wrS + mt * 16] = h;
    }
    __syncthreads();
    {
        f32x4 a2A[2] = {}, a2B[2] = {};
        gemm(sCA, WcF, a2A);
        gemm(sCB, WcF, a2B);
        // e2 with cue (ec3_prev = 0 -> e3 = clip(cue))
        #pragma unroll
        for (int mt = 0; mt < 2; ++mt) {
            const int f0 = wb + mt * 16 + quad * 4;
            const f32x4 cA = *(const f32x4*)&cue[(row0 + L) * 256 + f0];
            const f32x4 cB = *(const f32x4*)&cue[(row0 + 16 + L) * 256 + f0];
            bf16x4 hA, hB;
            #pragma unroll
            for (int r = 0; r < 4; ++r) {
                ec5A[mt][r] = fminf(fmaxf(ec5A[mt][r] + a2A[mt][r], 0.0f), 1.0f);
                ec5B[mt][r] = fminf(fmaxf(ec5B[mt][r] + a2B[mt][r], 0.0f), 1.0f);
                ec3A[mt][r] = fminf(fmaxf(cA[r], 0.0f), 1.0f);
                ec3B[mt][r] = fminf(fmaxf(cB[r], 0.0f), 1.0f);
                hA[r] = (__bf16)ec3A[mt][r];
                hB[r] = (__bf16)ec3B[mt][r];
            }
            *(bf16x4*)&sEA[wrS + mt * 16] = hA;
            *(bf16x4*)&sEB[wrS + mt * 16] = hB;
        }
    }
    __syncthreads();

    // pipeline prime: G1_A(t=1)
    f32x4 acc1A[2] = {};
    gemm(sEA, WapF, acc1A);

    // ===== steady state t = 1..98 =====
    for (int t = 1; t <= 98; ++t) {
        const float* bp = &sBasal[t * 256 + wb + quad * 4];
        f32x4 bas[2] = { *(const f32x4*)bp, *(const f32x4*)(bp + 16) };

        // P1: G1_B(t) | e1_A(t)
        f32x4 acc1B[2] = {};
        gemm(sEB, WapF, acc1B);
        e1(acc1A, bas, sCA);
        __syncthreads();

        // P2: G2_A(t) | e1_B(t)
        f32x4 acc2A[2] = {};
        gemm(sCA, WcF, acc2A);
        e1(acc1B, bas, sCB);
        __syncthreads();

        // P3: G2_B(t) | e2_A(t)
        f32x4 acc2B[2] = {};
        gemm(sCB, WcF, acc2B);
        e2(acc2A, ec5A, ec3A, sEA);
        __syncthreads();

        // P4: G1_A(t+1) | e2_B(t)
        acc1A[0] = f32x4{}; acc1A[1] = f32x4{};
        gemm(sEA, WapF, acc1A);
        e2(acc2B, ec5B, ec3B, sEB);
        __syncthreads();
    }

    // ===== t = 99 (peeled): only ca1 needed -> G1 + e1 + Waction partial dot =====
    {
        const float* bp = &sBasal[99 * 256 + wb + quad * 4];
        f32x4 bas[2] = { *(const f32x4*)bp, *(const f32x4*)(bp + 16) };
        f32x4 acc1B[2] = {};
        gemm(sEB, WapF, acc1B);

        float pA0 = 0.f, pA1 = 0.f, pB0 = 0.f, pB1 = 0.f;
        #pragma unroll
        for (int mt = 0; mt < 2; ++mt) {
            #pragma unroll
            for (int r = 0; r < 4; ++r) {
                const int f = wb + mt * 16 + quad * 4 + r;
                const f32x2 w = *(const f32x2*)&Wact[f * 2];
                const float sA = __builtin_amdgcn_rcpf(1.0f + __expf(-acc1A[mt][r]));
                const float cA = fmaxf(fmaf(bas[mt][r], 1.0f + sA, nb[mt][r]), 0.0f);
                const float sB = __builtin_amdgcn_rcpf(1.0f + __expf(-acc1B[mt][r]));
                const float cB = fmaxf(fmaf(bas[mt][r], 1.0f + sB, nb[mt][r]), 0.0f);
                pA0 += cA * w[0]; pA1 += cA * w[1];
                pB0 += cB * w[0]; pB1 += cB * w[1];
            }
        }
        const int grp = wave * 4 + quad;
        sPart[((0 * 16 + L) * 2 + 0) * 32 + grp] = pA0;
        sPart[((0 * 16 + L) * 2 + 1) * 32 + grp] = pA1;
        sPart[((1 * 16 + L) * 2 + 0) * 32 + grp] = pB0;
        sPart[((1 * 16 + L) * 2 + 1) * 32 + grp] = pB1;
    }
    __syncthreads();
    if (tid < 64) {
        const int tile = tid >> 5, l = (tid >> 1) & 15, a = tid & 1;
        float s = 0.f;
        #pragma unroll 8
        for (int g = 0; g < 32; ++g)
            s += sPart[((tile * 16 + l) * 2 + a) * 32 + g];
        out[(row0 + tile * 16 + l) * 2 + a] = s;
    }
}

extern "C" void kernel_launch(void* const* d_in, const int* in_sizes, int n_in,
                              void* d_out, int out_size, void* d_ws, size_t ws_size,
                              hipStream_t stream) {
    const float* cue      = (const float*)d_in[0];
    const float* ec5_init = (const float*)d_in[1];
    const float* Wapical  = (const float*)d_in[2];
    const float* Wbasal   = (const float*)d_in[3];
    const float* Wca1ec5  = (const float*)d_in[4];
    const float* Waction  = (const float*)d_in[5];
    const float* ca1bias  = (const float*)d_in[6];
    float* out = (float*)d_out;
    float* basal = (float*)d_ws;   // 100*256 fp32 = 100 KB

    basal_kernel<<<100, 256, 0, stream>>>(Wbasal, basal);
    rnn_kernel<<<32768 / 32, 512, 0, stream>>>(cue, ec5_init, Wapical, Wca1ec5,
                                               Waction, ca1bias, basal, out);
}